// Round 6
// baseline (454.444 us; speedup 1.0000x reference)
//
#include <hip/hip_runtime.h>
#include <math.h>

namespace {
constexpr int B_    = 8;
constexpr int NIN   = 32;
constexpr int H_    = 14;
constexpr int CIN   = 8;
constexpr int C_    = 32;
constexpr int COUT  = 16;
constexpr int R_    = 288;
constexpr int W_    = 12;
constexpr int NITER = 3;
constexpr size_t XSUB = (size_t)NIN * H_ * H_ * CIN;   // x stride per batch elem
}

__device__ __forceinline__ float dot4(const float4 a, const float4 b) {
    return fmaf(a.x, b.x, fmaf(a.y, b.y, fmaf(a.z, b.z, a.w * b.w)));
}

// Priors for (r, outputs og*4..og*4+3), batch elems b0 and b0+1; W float4s
// read once and shared by both subs. All loads issued up front (MLP).
__device__ __forceinline__ void prior_one(const float* __restrict__ x0,
                                          const float* __restrict__ rwc,
                                          int r, int p, int q, int og,
                                          float4& a0, float4& a1)
{
    const int n   = r / 9;
    const int rem = r - n * 9;
    const int kh  = rem / 3;
    const int kw  = rem - kh * 3;
    const float* xp = x0 + ((n * H_ + (p + kh)) * H_ + (q + kw)) * CIN;
    const float4 xa = *(const float4*)xp;
    const float4 xb = *(const float4*)(xp + 4);
    const float4 ya = *(const float4*)(xp + XSUB);
    const float4 yb = *(const float4*)(xp + XSUB + 4);
    const float xs0[8] = {xa.x, xa.y, xa.z, xa.w, xb.x, xb.y, xb.z, xb.w};
    const float xs1[8] = {ya.x, ya.y, ya.z, ya.w, yb.x, yb.y, yb.z, yb.w};
    const float4* wp = (const float4*)(rwc + (size_t)r * CIN * COUT) + og;
    float4 r0 = make_float4(0.f, 0.f, 0.f, 0.f);
    float4 r1 = make_float4(0.f, 0.f, 0.f, 0.f);
    #pragma unroll
    for (int i = 0; i < CIN; ++i) {
        const float4 wv = wp[i * 4];
        r0.x = fmaf(xs0[i], wv.x, r0.x);  r1.x = fmaf(xs1[i], wv.x, r1.x);
        r0.y = fmaf(xs0[i], wv.y, r0.y);  r1.y = fmaf(xs1[i], wv.y, r1.y);
        r0.z = fmaf(xs0[i], wv.z, r0.z);  r1.z = fmaf(xs1[i], wv.z, r1.z);
        r0.w = fmaf(xs0[i], wv.w, r0.w);  r1.w = fmaf(xs1[i], wv.w, r1.w);
    }
    a0 = r0; a1 = r1;
}

// One block of 512 threads per (c, b-pair, p, q). Priors AND logits live in
// registers. Thread (og = tid&3, rl = tid>>2 in 0..127) owns r = rl + 128j
// (j=0,1; + r = 256+rl for rl<32 — wave-uniform) x outputs og*4..og*4+3 x
// both batch elems: 24 acc regs/thread (vs 40 at 256 threads) -> ~5-6
// waves/SIMD instead of 4. After the og-butterfly every lane of an og-quad
// holds the full sum_o(pri*v), so logits/exp are maintained redundantly per
// lane — no LDS logits/probs. 2 barriers per iter.
// NOTE: plain launch_bounds — forcing waves/EU (R4) spilled to scratch
// (hbm_bytes 27MB->4.5GB, 340->1089us). Let the allocator decide.
__global__ __launch_bounds__(512)
void caps_route6(const float* __restrict__ x,
                 const float* __restrict__ rw,
                 float* __restrict__ out)
{
    const int tid = threadIdx.x;
    const int p  = blockIdx.x / W_;
    const int q  = blockIdx.x % W_;
    const int b0 = blockIdx.y * 2;
    const int c  = blockIdx.z;

    __shared__ float sRed[8][2][16];   // per-wave partial s
    __shared__ float redE[2][8];       // per-wave sum of exp
    __shared__ float vS[2][16];        // squashed v broadcast

    const int og   = tid & 3;
    const int rl   = tid >> 2;         // 0..127
    const int lane = tid & 63;
    const int wv   = tid >> 6;         // 0..7
    const bool hasJ2 = (rl < 32);      // waves 0,1 — wave-uniform predicate

    // ---- priors in registers
    const float* x0  = x + (size_t)b0 * XSUB;
    const float* rwc = rw + (size_t)c * R_ * CIN * COUT;
    float4 acc[3][2];
    #pragma unroll
    for (int j = 0; j < 2; ++j)
        prior_one(x0, rwc, rl + 128 * j, p, q, og, acc[j][0], acc[j][1]);
    if (hasJ2)
        prior_one(x0, rwc, 256 + rl, p, q, og, acc[2][0], acc[2][1]);

    // logits, register-resident (identical across each og-quad)
    float lg0[3] = {0.f, 0.f, 0.f};
    float lg1[3] = {0.f, 0.f, 0.f};

    for (int it = 0; it < NITER; ++it) {
        float4 s0 = make_float4(0.f, 0.f, 0.f, 0.f);
        float4 s1 = make_float4(0.f, 0.f, 0.f, 0.f);
        float se0 = 0.f, se1 = 0.f;

        if (it == 0) {
            // probs uniform: s = sum_r pri (1/R folded into squash)
            #pragma unroll
            for (int j = 0; j < 2; ++j) {
                s0.x += acc[j][0].x;  s1.x += acc[j][1].x;
                s0.y += acc[j][0].y;  s1.y += acc[j][1].y;
                s0.z += acc[j][0].z;  s1.z += acc[j][1].z;
                s0.w += acc[j][0].w;  s1.w += acc[j][1].w;
            }
            if (hasJ2) {
                s0.x += acc[2][0].x;  s1.x += acc[2][1].x;
                s0.y += acc[2][0].y;  s1.y += acc[2][1].y;
                s0.z += acc[2][0].z;  s1.z += acc[2][1].z;
                s0.w += acc[2][0].w;  s1.w += acc[2][1].w;
            }
        } else {
            const float4 v0 = *(const float4*)&vS[0][og * 4];
            const float4 v1 = *(const float4*)&vS[1][og * 4];
            #pragma unroll
            for (int j = 0; j < 2; ++j) {
                float d0 = dot4(acc[j][0], v0);
                float d1 = dot4(acc[j][1], v1);
                d0 += __shfl_xor(d0, 1, 64);  d1 += __shfl_xor(d1, 1, 64);
                d0 += __shfl_xor(d0, 2, 64);  d1 += __shfl_xor(d1, 2, 64);
                lg0[j] += d0;                 lg1[j] += d1;
                const float e0 = __expf(lg0[j]);
                const float e1 = __expf(lg1[j]);
                se0 += e0;                    se1 += e1;
                s0.x = fmaf(e0, acc[j][0].x, s0.x);  s1.x = fmaf(e1, acc[j][1].x, s1.x);
                s0.y = fmaf(e0, acc[j][0].y, s0.y);  s1.y = fmaf(e1, acc[j][1].y, s1.y);
                s0.z = fmaf(e0, acc[j][0].z, s0.z);  s1.z = fmaf(e1, acc[j][1].z, s1.z);
                s0.w = fmaf(e0, acc[j][0].w, s0.w);  s1.w = fmaf(e1, acc[j][1].w, s1.w);
            }
            if (hasJ2) {
                float d0 = dot4(acc[2][0], v0);
                float d1 = dot4(acc[2][1], v1);
                d0 += __shfl_xor(d0, 1, 64);  d1 += __shfl_xor(d1, 1, 64);
                d0 += __shfl_xor(d0, 2, 64);  d1 += __shfl_xor(d1, 2, 64);
                lg0[2] += d0;                 lg1[2] += d1;
                const float e0 = __expf(lg0[2]);
                const float e1 = __expf(lg1[2]);
                se0 += e0;                    se1 += e1;
                s0.x = fmaf(e0, acc[2][0].x, s0.x);  s1.x = fmaf(e1, acc[2][1].x, s1.x);
                s0.y = fmaf(e0, acc[2][0].y, s0.y);  s1.y = fmaf(e1, acc[2][1].y, s1.y);
                s0.z = fmaf(e0, acc[2][0].z, s0.z);  s1.z = fmaf(e1, acc[2][1].z, s1.z);
                s0.w = fmaf(e0, acc[2][0].w, s0.w);  s1.w = fmaf(e1, acc[2][1].w, s1.w);
            }
            // se identical across og lanes -> reduce over rl bits only
            #pragma unroll
            for (int off = 4; off <= 32; off <<= 1) {
                se0 += __shfl_xor(se0, off, 64);
                se1 += __shfl_xor(se1, off, 64);
            }
            if (lane == 0) { redE[0][wv] = se0; redE[1][wv] = se1; }
        }

        // reduce s over rl bits within wave (1/sum_e applied in squash)
        #pragma unroll
        for (int off = 4; off <= 32; off <<= 1) {
            s0.x += __shfl_xor(s0.x, off, 64);  s1.x += __shfl_xor(s1.x, off, 64);
            s0.y += __shfl_xor(s0.y, off, 64);  s1.y += __shfl_xor(s1.y, off, 64);
            s0.z += __shfl_xor(s0.z, off, 64);  s1.z += __shfl_xor(s1.z, off, 64);
            s0.w += __shfl_xor(s0.w, off, 64);  s1.w += __shfl_xor(s1.w, off, 64);
        }
        if (lane < 4) {   // lane == og here
            *(float4*)&sRed[wv][0][lane * 4] = s0;
            *(float4*)&sRed[wv][1][lane * 4] = s1;
        }
        __syncthreads();

        // ---- squash (32 threads: sb, o); inv folded in here
        if (tid < 32) {
            const int sb = tid >> 4;
            const int o  = tid & 15;
            float sumE = 0.f, s = 0.f;
            #pragma unroll
            for (int w8 = 0; w8 < 8; ++w8) {
                sumE += redE[sb][w8];
                s    += sRed[w8][sb][o];
            }
            const float inv = (it == 0) ? (1.0f / (float)R_) : (1.0f / sumE);
            s *= inv;
            float sn = s * s;
            #pragma unroll
            for (int off = 1; off <= 8; off <<= 1) sn += __shfl_xor(sn, off, 64);
            const float v = s * (sqrtf(sn) / (1.0f + sn));
            if (it == NITER - 1) {
                out[((((size_t)(b0 + sb) * C_ + c) * W_ + p) * W_ + q) * COUT + o] = v;
            } else {
                vS[sb][o] = v;
            }
        }
        if (it == NITER - 1) break;
        __syncthreads();   // vS visible to all before next iteration
    }
}

extern "C" void kernel_launch(void* const* d_in, const int* in_sizes, int n_in,
                              void* d_out, int out_size, void* d_ws, size_t ws_size,
                              hipStream_t stream) {
    const float* x  = (const float*)d_in[0];
    const float* rw = (const float*)d_in[1];
    float* out = (float*)d_out;
    dim3 grid(W_ * W_, B_ / 2, C_);
    caps_route6<<<grid, 512, 0, stream>>>(x, rw, out);
}

// Round 7
// 305.235 us; speedup vs baseline: 1.4888x; 1.4888x over previous
//
#include <hip/hip_runtime.h>
#include <math.h>

namespace {
constexpr int B_    = 8;
constexpr int NIN   = 32;
constexpr int H_    = 14;
constexpr int CIN   = 8;
constexpr int C_    = 32;
constexpr int COUT  = 16;
constexpr int R_    = 288;
constexpr int W_    = 12;
constexpr int NITER = 3;
constexpr size_t XSUB = (size_t)NIN * H_ * H_ * CIN;   // x stride per batch elem
}

typedef unsigned int u32;
typedef const __attribute__((address_space(1))) u32* as1_u32p;
typedef __attribute__((address_space(3))) u32* as3_u32p;

__device__ __forceinline__ void async_copy16(const void* g, void* l) {
    __builtin_amdgcn_global_load_lds((as1_u32p)g, (as3_u32p)l, 16, 0, 0);
}

__device__ __forceinline__ float dot4(const float4 a, const float4 b) {
    return fmaf(a.x, b.x, fmaf(a.y, b.y, fmaf(a.z, b.z, a.w * b.w)));
}

// One block (256 thr) per (c, b-pair, p, q). W[c] is streamed through a
// single 32 KB LDS buffer in 5 chunks (4x64r + 1x32r) via global_load_lds
// (async, zero VGPR cost -> full-chunk MLP; R5's register-held W serialized
// into ~4 latency rounds). Staging permutes global addresses so the LDS
// layout is [i][r][og]: compute reads wbuf[i*256+tid] = contiguous
// lane-ordered ds_read_b128, conflict-free, imm offsets.
// Priors + logits in registers; routing = R5 structure (2 barriers/iter).
// R4 lesson: no forced waves/EU (spills). R6 lesson: don't trade per-wave
// MLP for occupancy.
__global__ __launch_bounds__(256)
void caps_route7(const float* __restrict__ x,
                 const float* __restrict__ rw,
                 float* __restrict__ out)
{
    const int tid = threadIdx.x;
    const int p  = blockIdx.x / W_;
    const int q  = blockIdx.x % W_;
    const int b0 = blockIdx.y * 2;
    const int c  = blockIdx.z;

    __shared__ float4 wbuf[2048];      // 32 KB W staging chunk
    __shared__ float sRed[4][2][16];   // per-wave partial s
    __shared__ float redE[2][4];       // per-wave sum of exp
    __shared__ float vS[2][16];        // squashed v broadcast

    const int og   = tid & 3;
    const int rl   = tid >> 2;         // 0..63
    const int lane = tid & 63;
    const int wv   = tid >> 6;
    const bool hasJ4 = (rl < 32);      // waves 0,1 — wave-uniform predicate

    const float* x0 = x + (size_t)b0 * XSUB;
    const float4* rwcF4 = (const float4*)(rw + (size_t)c * R_ * CIN * COUT);

    float4 acc[5][2];

    // ---- priors: 5 chunks streamed through LDS
    #pragma unroll
    for (int k = 0; k < 5; ++k) {
        const int iters  = (k < 4) ? 8 : 4;       // staging wave-iters
        const int chmask = (k < 4) ? 63 : 31;     // CH-1
        const int ishift = (k < 4) ? 8 : 7;       // log2(CH*4)
        const int stride = (k < 4) ? 256 : 128;   // f4 per i-plane

        if (k) __syncthreads();        // prev chunk fully consumed by all waves

        // x loads for this chunk (issue early; hidden behind staging drain)
        const int r = 64 * k + rl;     // k=4 -> 256+rl, valid only rl<32
        const bool act = (k < 4) || hasJ4;
        float4 xa, xb, ya, yb;
        if (act) {
            const int n = r / 9, rem = r - n * 9;
            const int kh = rem / 3, kw = rem - kh * 3;
            const float* xp = x0 + ((n * H_ + (p + kh)) * H_ + (q + kw)) * CIN;
            xa = *(const float4*)xp;          xb = *(const float4*)(xp + 4);
            ya = *(const float4*)(xp + XSUB); yb = *(const float4*)(xp + XSUB + 4);
        }

        // stage W chunk k: LDS slot s = i*CH*4 + r*4 + og holds global f4
        // (r*32 + i*4 + og); staging iter t covers slots t*256 + tid.
        const float4* gchunk = rwcF4 + k * 2048;
        #pragma unroll
        for (int t = 0; t < iters; ++t) {
            const int s  = t * 256 + tid;
            const int rr = (s >> 2) & chmask;
            const int ii = s >> ishift;
            const int g4 = rr * 32 + ii * 4 + (s & 3);
            async_copy16(gchunk + g4,
                         (char*)wbuf + (t * 256 + (tid & 192)) * 16);
        }
        __syncthreads();               // staging (vmcnt drain) + x arrived

        if (act) {
            const float xs0[8] = {xa.x, xa.y, xa.z, xa.w, xb.x, xb.y, xb.z, xb.w};
            const float xs1[8] = {ya.x, ya.y, ya.z, ya.w, yb.x, yb.y, yb.z, yb.w};
            float4 r0 = make_float4(0.f, 0.f, 0.f, 0.f);
            float4 r1 = make_float4(0.f, 0.f, 0.f, 0.f);
            #pragma unroll
            for (int i = 0; i < 8; ++i) {
                const float4 wvv = wbuf[i * stride + tid];  // ds_read_b128, conflict-free
                r0.x = fmaf(xs0[i], wvv.x, r0.x);  r1.x = fmaf(xs1[i], wvv.x, r1.x);
                r0.y = fmaf(xs0[i], wvv.y, r0.y);  r1.y = fmaf(xs1[i], wvv.y, r1.y);
                r0.z = fmaf(xs0[i], wvv.z, r0.z);  r1.z = fmaf(xs1[i], wvv.z, r1.z);
                r0.w = fmaf(xs0[i], wvv.w, r0.w);  r1.w = fmaf(xs1[i], wvv.w, r1.w);
            }
            acc[k][0] = r0;  acc[k][1] = r1;
        }
    }
    __syncthreads();   // last chunk reads done before routing reuses nothing, but keep order clean

    // logits, register-resident (identical across each og-quad)
    float lg0[5] = {0.f, 0.f, 0.f, 0.f, 0.f};
    float lg1[5] = {0.f, 0.f, 0.f, 0.f, 0.f};

    for (int it = 0; it < NITER; ++it) {
        float4 s0 = make_float4(0.f, 0.f, 0.f, 0.f);
        float4 s1 = make_float4(0.f, 0.f, 0.f, 0.f);
        float se0 = 0.f, se1 = 0.f;

        if (it == 0) {
            // probs uniform: s = sum_r pri (1/R folded into squash)
            #pragma unroll
            for (int j = 0; j < 4; ++j) {
                s0.x += acc[j][0].x;  s1.x += acc[j][1].x;
                s0.y += acc[j][0].y;  s1.y += acc[j][1].y;
                s0.z += acc[j][0].z;  s1.z += acc[j][1].z;
                s0.w += acc[j][0].w;  s1.w += acc[j][1].w;
            }
            if (hasJ4) {
                s0.x += acc[4][0].x;  s1.x += acc[4][1].x;
                s0.y += acc[4][0].y;  s1.y += acc[4][1].y;
                s0.z += acc[4][0].z;  s1.z += acc[4][1].z;
                s0.w += acc[4][0].w;  s1.w += acc[4][1].w;
            }
        } else {
            const float4 v0 = *(const float4*)&vS[0][og * 4];
            const float4 v1 = *(const float4*)&vS[1][og * 4];
            #pragma unroll
            for (int j = 0; j < 4; ++j) {
                float d0 = dot4(acc[j][0], v0);
                float d1 = dot4(acc[j][1], v1);
                d0 += __shfl_xor(d0, 1, 64);  d1 += __shfl_xor(d1, 1, 64);
                d0 += __shfl_xor(d0, 2, 64);  d1 += __shfl_xor(d1, 2, 64);
                lg0[j] += d0;                 lg1[j] += d1;
                const float e0 = __expf(lg0[j]);
                const float e1 = __expf(lg1[j]);
                se0 += e0;                    se1 += e1;
                s0.x = fmaf(e0, acc[j][0].x, s0.x);  s1.x = fmaf(e1, acc[j][1].x, s1.x);
                s0.y = fmaf(e0, acc[j][0].y, s0.y);  s1.y = fmaf(e1, acc[j][1].y, s1.y);
                s0.z = fmaf(e0, acc[j][0].z, s0.z);  s1.z = fmaf(e1, acc[j][1].z, s1.z);
                s0.w = fmaf(e0, acc[j][0].w, s0.w);  s1.w = fmaf(e1, acc[j][1].w, s1.w);
            }
            if (hasJ4) {
                float d0 = dot4(acc[4][0], v0);
                float d1 = dot4(acc[4][1], v1);
                d0 += __shfl_xor(d0, 1, 64);  d1 += __shfl_xor(d1, 1, 64);
                d0 += __shfl_xor(d0, 2, 64);  d1 += __shfl_xor(d1, 2, 64);
                lg0[4] += d0;                 lg1[4] += d1;
                const float e0 = __expf(lg0[4]);
                const float e1 = __expf(lg1[4]);
                se0 += e0;                    se1 += e1;
                s0.x = fmaf(e0, acc[4][0].x, s0.x);  s1.x = fmaf(e1, acc[4][1].x, s1.x);
                s0.y = fmaf(e0, acc[4][0].y, s0.y);  s1.y = fmaf(e1, acc[4][1].y, s1.y);
                s0.z = fmaf(e0, acc[4][0].z, s0.z);  s1.z = fmaf(e1, acc[4][1].z, s1.z);
                s0.w = fmaf(e0, acc[4][0].w, s0.w);  s1.w = fmaf(e1, acc[4][1].w, s1.w);
            }
            // se identical across og lanes -> reduce over rl bits only
            #pragma unroll
            for (int off = 4; off <= 32; off <<= 1) {
                se0 += __shfl_xor(se0, off, 64);
                se1 += __shfl_xor(se1, off, 64);
            }
            if (lane == 0) { redE[0][wv] = se0; redE[1][wv] = se1; }
        }

        // reduce s over rl bits within wave (1/sum_e applied in squash)
        #pragma unroll
        for (int off = 4; off <= 32; off <<= 1) {
            s0.x += __shfl_xor(s0.x, off, 64);  s1.x += __shfl_xor(s1.x, off, 64);
            s0.y += __shfl_xor(s0.y, off, 64);  s1.y += __shfl_xor(s1.y, off, 64);
            s0.z += __shfl_xor(s0.z, off, 64);  s1.z += __shfl_xor(s1.z, off, 64);
            s0.w += __shfl_xor(s0.w, off, 64);  s1.w += __shfl_xor(s1.w, off, 64);
        }
        if (lane < 4) {   // lane == og here
            *(float4*)&sRed[wv][0][lane * 4] = s0;
            *(float4*)&sRed[wv][1][lane * 4] = s1;
        }
        __syncthreads();

        // ---- squash (32 threads: sb, o); inv folded in here
        if (tid < 32) {
            const int sb = tid >> 4;
            const int o  = tid & 15;
            const float inv = (it == 0)
                ? (1.0f / (float)R_)
                : 1.0f / (redE[sb][0] + redE[sb][1] + redE[sb][2] + redE[sb][3]);
            float s = (sRed[0][sb][o] + sRed[1][sb][o]
                     + sRed[2][sb][o] + sRed[3][sb][o]) * inv;
            float sn = s * s;
            #pragma unroll
            for (int off = 1; off <= 8; off <<= 1) sn += __shfl_xor(sn, off, 64);
            const float v = s * (sqrtf(sn) / (1.0f + sn));
            if (it == NITER - 1) {
                out[((((size_t)(b0 + sb) * C_ + c) * W_ + p) * W_ + q) * COUT + o] = v;
            } else {
                vS[sb][o] = v;
            }
        }
        if (it == NITER - 1) break;
        __syncthreads();   // vS visible to all before next iteration
    }
}

extern "C" void kernel_launch(void* const* d_in, const int* in_sizes, int n_in,
                              void* d_out, int out_size, void* d_ws, size_t ws_size,
                              hipStream_t stream) {
    const float* x  = (const float*)d_in[0];
    const float* rw = (const float*)d_in[1];
    float* out = (float*)d_out;
    dim3 grid(W_ * W_, B_ / 2, C_);
    caps_route7<<<grid, 256, 0, stream>>>(x, rw, out);
}

// Round 8
// 219.316 us; speedup vs baseline: 2.0721x; 1.3918x over previous
//
#include <hip/hip_runtime.h>
#include <math.h>

namespace {
constexpr int B_    = 8;
constexpr int NIN   = 32;
constexpr int H_    = 14;
constexpr int CIN   = 8;
constexpr int C_    = 32;
constexpr int COUT  = 16;
constexpr int R_    = 288;
constexpr int W_    = 12;
constexpr int NITER = 3;
constexpr int CH    = 32;              // r per chunk
constexpr int NCH   = 9;               // 288/32, uniform chunks
constexpr size_t XSUB = (size_t)NIN * H_ * H_ * CIN;   // x stride per batch elem
}

typedef unsigned int u32;
typedef const __attribute__((address_space(1))) u32* as1_u32p;
typedef __attribute__((address_space(3))) u32* as3_u32p;

__device__ __forceinline__ void async_copy16(const void* g, void* l) {
    __builtin_amdgcn_global_load_lds((as1_u32p)g, (as3_u32p)l, 16, 0, 0);
}
__device__ __forceinline__ float dot4(const float4 a, const float4 b) {
    return fmaf(a.x, b.x, fmaf(a.y, b.y, fmaf(a.z, b.z, a.w * b.w)));
}

// One block (256 thr) per (c, b-QUAD, p, q): 4 batch elems share each W[c]
// byte (L2 W-traffic 2.7 GB -> 1.36 GB vs R7; staging writes + W ds_reads +
// barriers per position halve). W and x both stream through double-buffered
// LDS via global_load_lds; stage(k+1) is issued right AFTER the barrier that
// certifies stage(k), so chunk k+1's loads fly during compute(k) and the
// per-chunk vmcnt drain vanishes (the compiler's vmcnt(0)-at-barrier then
// only waits for already-landed loads). One barrier per chunk.
// Thread (og=tid&3, cr=(tid>>2)&31, sh=rl>>5): owns r = k*32+cr for subs
// {2sh, 2sh+1}: acc[9][2] f4 + lg[9][2] in registers.
// Lessons kept: no forced waves/EU (R4 spill); per-wave MLP via zero-VGPR
// global_load_lds queue (R6/R7); priors fp32 everywhere (R2).
__global__ __launch_bounds__(256)
void caps_route8(const float* __restrict__ x,
                 const float* __restrict__ rw,
                 float* __restrict__ out)
{
    const int tid = threadIdx.x;
    const int p  = blockIdx.x / W_;
    const int q  = blockIdx.x % W_;
    const int b0 = blockIdx.y * 4;
    const int c  = blockIdx.z;

    __shared__ float4 wbuf[2][1024];   // [buf][i(8)][cr(32)][og(4)]  16 KB each
    __shared__ float4 xbuf[2][256];    // [buf][sub(4)][half(2)][cr(32)] 4 KB each
    __shared__ float  sRed[4][2][16];  // [wave][local sub][o]
    __shared__ float  redE[4][2];      // [wave][local sub]
    __shared__ float  vS[4][16];       // [sub][o]

    const int og   = tid & 3;
    const int rl   = tid >> 2;     // 0..63
    const int cr   = rl & 31;      // chunk-local r
    const int sh   = rl >> 5;      // wave-uniform: waves 0,1 -> subs 0,1; waves 2,3 -> subs 2,3
    const int lane = tid & 63;
    const int wv   = tid >> 6;

    const float* x0 = x + (size_t)b0 * XSUB;
    const float4* rwcF4 = (const float4*)(rw + (size_t)c * R_ * CIN * COUT);

    // x staging slot params: slot s = tid = xsub*64 + xhalf*32 + xcr
    const int xsub  = wv;
    const int xhalf = (tid >> 5) & 1;
    const int xcr   = tid & 31;

    float4 acc[NCH][2];

    auto stage = [&](int k, int buf) {
        // W chunk k: slot s = t*256+tid -> [ii=s>>7][wcr=(s>>2)&31][wog=s&3],
        // global f4 = wcr*32 + ii*4 + wog (chunk base k*1024 f4)
        const float4* gchunk = rwcF4 + (size_t)k * (CH * 32);
        #pragma unroll
        for (int t = 0; t < 4; ++t) {
            const int s   = t * 256 + tid;
            const int ii  = s >> 7;
            const int wcr = (s >> 2) & 31;
            async_copy16(gchunk + (wcr * 32 + ii * 4 + (s & 3)),
                         (char*)&wbuf[buf][0] + (t * 256 + (tid & 192)) * 16);
        }
        // x chunk k: slot tid -> (xsub, xhalf, xcr); r = k*32+xcr
        const int r  = k * CH + xcr;
        const int n  = r / 9, rem = r - n * 9;
        const int kh = rem / 3, kw = rem - kh * 3;
        const float* xp = x0 + (size_t)xsub * XSUB
                        + ((n * H_ + (p + kh)) * H_ + (q + kw)) * CIN + xhalf * 4;
        async_copy16(xp, (char*)&xbuf[buf][0] + (tid & 192) * 16);
    };

    stage(0, 0);
    #pragma unroll
    for (int k = 0; k < NCH; ++k) {
        __syncthreads();               // stage(k) arrived; buf[(k+1)&1] consumed by all
        if (k + 1 < NCH) stage(k + 1, (k + 1) & 1);
        const int buf = k & 1;
        const float4* wb  = &wbuf[buf][0];
        const float4* xbp = &xbuf[buf][0];
        // subs 2sh (A) and 2sh+1 (B); [sub][half][cr] layout -> 2-way bank alias (free)
        const float4 xA0 = xbp[sh * 128 + cr];
        const float4 xA1 = xbp[sh * 128 + 32 + cr];
        const float4 xB0 = xbp[sh * 128 + 64 + cr];
        const float4 xB1 = xbp[sh * 128 + 96 + cr];
        const float fA[8] = {xA0.x, xA0.y, xA0.z, xA0.w, xA1.x, xA1.y, xA1.z, xA1.w};
        const float fB[8] = {xB0.x, xB0.y, xB0.z, xB0.w, xB1.x, xB1.y, xB1.z, xB1.w};
        float4 a0 = make_float4(0.f, 0.f, 0.f, 0.f);
        float4 a1 = make_float4(0.f, 0.f, 0.f, 0.f);
        #pragma unroll
        for (int i = 0; i < 8; ++i) {
            const float4 wv4 = wb[i * 128 + cr * 4 + og];   // 64 consecutive f4/wave: conflict-free b128
            a0.x = fmaf(fA[i], wv4.x, a0.x);  a1.x = fmaf(fB[i], wv4.x, a1.x);
            a0.y = fmaf(fA[i], wv4.y, a0.y);  a1.y = fmaf(fB[i], wv4.y, a1.y);
            a0.z = fmaf(fA[i], wv4.z, a0.z);  a1.z = fmaf(fB[i], wv4.z, a1.z);
            a0.w = fmaf(fA[i], wv4.w, a0.w);  a1.w = fmaf(fB[i], wv4.w, a1.w);
        }
        acc[k][0] = a0;  acc[k][1] = a1;
    }

    const int sA = sh * 2;             // this thread's first sub
    float lgA[NCH], lgB[NCH];
    #pragma unroll
    for (int j = 0; j < NCH; ++j) { lgA[j] = 0.f; lgB[j] = 0.f; }

    for (int it = 0; it < NITER; ++it) {
        float4 s0 = make_float4(0.f, 0.f, 0.f, 0.f);
        float4 s1 = make_float4(0.f, 0.f, 0.f, 0.f);
        float se0 = 0.f, se1 = 0.f;

        if (it == 0) {
            #pragma unroll
            for (int j = 0; j < NCH; ++j) {
                s0.x += acc[j][0].x;  s1.x += acc[j][1].x;
                s0.y += acc[j][0].y;  s1.y += acc[j][1].y;
                s0.z += acc[j][0].z;  s1.z += acc[j][1].z;
                s0.w += acc[j][0].w;  s1.w += acc[j][1].w;
            }
        } else {
            const float4 v0 = *(const float4*)&vS[sA][og * 4];
            const float4 v1 = *(const float4*)&vS[sA + 1][og * 4];
            #pragma unroll
            for (int j = 0; j < NCH; ++j) {
                float d0 = dot4(acc[j][0], v0);
                float d1 = dot4(acc[j][1], v1);
                d0 += __shfl_xor(d0, 1, 64);  d1 += __shfl_xor(d1, 1, 64);
                d0 += __shfl_xor(d0, 2, 64);  d1 += __shfl_xor(d1, 2, 64);
                lgA[j] += d0;                 lgB[j] += d1;
                const float e0 = __expf(lgA[j]);
                const float e1 = __expf(lgB[j]);
                se0 += e0;                    se1 += e1;
                s0.x = fmaf(e0, acc[j][0].x, s0.x);  s1.x = fmaf(e1, acc[j][1].x, s1.x);
                s0.y = fmaf(e0, acc[j][0].y, s0.y);  s1.y = fmaf(e1, acc[j][1].y, s1.y);
                s0.z = fmaf(e0, acc[j][0].z, s0.z);  s1.z = fmaf(e1, acc[j][1].z, s1.z);
                s0.w = fmaf(e0, acc[j][0].w, s0.w);  s1.w = fmaf(e1, acc[j][1].w, s1.w);
            }
            // se identical across og lanes -> reduce over rl bits (2..5) only
            #pragma unroll
            for (int off = 4; off <= 32; off <<= 1) {
                se0 += __shfl_xor(se0, off, 64);
                se1 += __shfl_xor(se1, off, 64);
            }
            if (lane == 0) { redE[wv][0] = se0; redE[wv][1] = se1; }
        }

        // reduce s over rl bits within wave (1/sum_e folded into squash)
        #pragma unroll
        for (int off = 4; off <= 32; off <<= 1) {
            s0.x += __shfl_xor(s0.x, off, 64);  s1.x += __shfl_xor(s1.x, off, 64);
            s0.y += __shfl_xor(s0.y, off, 64);  s1.y += __shfl_xor(s1.y, off, 64);
            s0.z += __shfl_xor(s0.z, off, 64);  s1.z += __shfl_xor(s1.z, off, 64);
            s0.w += __shfl_xor(s0.w, off, 64);  s1.w += __shfl_xor(s1.w, off, 64);
        }
        if (lane < 4) {   // lane == og
            *(float4*)&sRed[wv][0][lane * 4] = s0;
            *(float4*)&sRed[wv][1][lane * 4] = s1;
        }
        __syncthreads();

        // ---- squash: 64 threads = (sub 0..3, o 0..15)
        if (tid < 64) {
            const int sub = tid >> 4;
            const int o   = tid & 15;
            const int g   = sub >> 1;      // wave-pair group
            const int l   = sub & 1;       // local sub within pair
            const float inv = (it == 0)
                ? (1.0f / (float)R_)
                : 1.0f / (redE[g * 2][l] + redE[g * 2 + 1][l]);
            float s = (sRed[g * 2][l][o] + sRed[g * 2 + 1][l][o]) * inv;
            float sn = s * s;
            #pragma unroll
            for (int off = 1; off <= 8; off <<= 1) sn += __shfl_xor(sn, off, 64);
            const float v = s * (sqrtf(sn) / (1.0f + sn));
            if (it == NITER - 1) {
                out[((((size_t)(b0 + sub) * C_ + c) * W_ + p) * W_ + q) * COUT + o] = v;
            } else {
                vS[sub][o] = v;
            }
        }
        if (it == NITER - 1) break;
        __syncthreads();   // vS visible before next iteration
    }
}

extern "C" void kernel_launch(void* const* d_in, const int* in_sizes, int n_in,
                              void* d_out, int out_size, void* d_ws, size_t ws_size,
                              hipStream_t stream) {
    const float* x  = (const float*)d_in[0];
    const float* rw = (const float*)d_in[1];
    float* out = (float*)d_out;
    dim3 grid(W_ * W_, B_ / 4, C_);
    caps_route8<<<grid, 256, 0, stream>>>(x, rw, out);
}

// Round 9
// 205.144 us; speedup vs baseline: 2.2152x; 1.0691x over previous
//
#include <hip/hip_runtime.h>
#include <math.h>

namespace {
constexpr int B_    = 8;
constexpr int NIN   = 32;
constexpr int H_    = 14;
constexpr int CIN   = 8;
constexpr int C_    = 32;
constexpr int COUT  = 16;
constexpr int R_    = 288;
constexpr int W_    = 12;
constexpr int NITER = 3;
constexpr int CH    = 32;              // r per chunk
constexpr int NCH   = 9;               // 288/32, uniform chunks
constexpr size_t XSUB = (size_t)NIN * H_ * H_ * CIN;   // x stride per batch elem
}

typedef unsigned int u32;
typedef const __attribute__((address_space(1))) u32* as1_u32p;
typedef __attribute__((address_space(3))) u32* as3_u32p;

__device__ __forceinline__ void async_copy16(const void* g, void* l) {
    __builtin_amdgcn_global_load_lds((as1_u32p)g, (as3_u32p)l, 16, 0, 0);
}
__device__ __forceinline__ float dot4(const float4 a, const float4 b) {
    return fmaf(a.x, b.x, fmaf(a.y, b.y, fmaf(a.z, b.z, a.w * b.w)));
}

// Quad-level butterfly adds on the VALU pipe (DPP quad_perm), replacing
// ds_swizzle shuffles — R8 analysis: DS pipe ~70% busy (staging reads +
// ~184 shfl/thread), VALU 41%. xor1 = quad_perm[1,0,3,2] = 0xB1,
// xor2 = quad_perm[2,3,0,1] = 0x4E. Bit-identical dataflow to shfl_xor.
__device__ __forceinline__ float dpp_add_xor1(float v) {
    int t = __builtin_amdgcn_update_dpp(0, __float_as_int(v), 0xB1, 0xF, 0xF, true);
    return v + __int_as_float(t);
}
__device__ __forceinline__ float dpp_add_xor2(float v) {
    int t = __builtin_amdgcn_update_dpp(0, __float_as_int(v), 0x4E, 0xF, 0xF, true);
    return v + __int_as_float(t);
}

// One block (256 thr) per (c, b-QUAD, p, q): 4 batch elems share each W[c]
// byte. W and x stream through double-buffered LDS via global_load_lds;
// stage(k+1) issues right AFTER the barrier certifying stage(k) so its loads
// fly during compute(k) — the vmcnt drain at the next barrier is free.
// Thread (og=tid&3, cr=(tid>>2)&31, sh=rl>>5) owns r=k*32+cr for subs
// {2sh,2sh+1}: acc[9][2] f4 + lg[9][2] in registers.
// Lessons: no forced waves/EU (R4 spill); keep per-wave MLP in the zero-VGPR
// global_load_lds queue (R6/R7); priors fp32 (R2); og-butterflies on DPP (R9).
__global__ __launch_bounds__(256)
void caps_route9(const float* __restrict__ x,
                 const float* __restrict__ rw,
                 float* __restrict__ out)
{
    const int tid = threadIdx.x;
    const int p  = blockIdx.x / W_;
    const int q  = blockIdx.x % W_;
    const int b0 = blockIdx.y * 4;
    const int c  = blockIdx.z;

    __shared__ float4 wbuf[2][1024];   // [buf][i(8)][cr(32)][og(4)]  16 KB each
    __shared__ float4 xbuf[2][256];    // [buf][sub(4)][half(2)][cr(32)] 4 KB each
    __shared__ float  sRed[4][2][16];  // [wave][local sub][o]
    __shared__ float  redE[4][2];      // [wave][local sub]
    __shared__ float  vS[4][16];       // [sub][o]

    const int og   = tid & 3;
    const int rl   = tid >> 2;     // 0..63
    const int cr   = rl & 31;      // chunk-local r
    const int sh   = rl >> 5;      // wave-uniform: waves 0,1 -> subs 0,1; waves 2,3 -> 2,3
    const int lane = tid & 63;
    const int wv   = tid >> 6;

    const float* x0 = x + (size_t)b0 * XSUB;
    const float4* rwcF4 = (const float4*)(rw + (size_t)c * R_ * CIN * COUT);

    // x staging slot params: slot s = tid = xsub*64 + xhalf*32 + xcr
    const int xsub  = wv;
    const int xhalf = (tid >> 5) & 1;
    const int xcr   = tid & 31;

    float4 acc[NCH][2];

    auto stage = [&](int k, int buf) {
        // W chunk k: slot s = t*256+tid -> [ii=s>>7][wcr=(s>>2)&31][wog=s&3],
        // global f4 = wcr*32 + ii*4 + wog (chunk base k*1024 f4)
        const float4* gchunk = rwcF4 + (size_t)k * (CH * 32);
        #pragma unroll
        for (int t = 0; t < 4; ++t) {
            const int s   = t * 256 + tid;
            const int ii  = s >> 7;
            const int wcr = (s >> 2) & 31;
            async_copy16(gchunk + (wcr * 32 + ii * 4 + (s & 3)),
                         (char*)&wbuf[buf][0] + (t * 256 + (tid & 192)) * 16);
        }
        // x chunk k: slot tid -> (xsub, xhalf, xcr); r = k*32+xcr
        const int r  = k * CH + xcr;
        const int n  = r / 9, rem = r - n * 9;
        const int kh = rem / 3, kw = rem - kh * 3;
        const float* xp = x0 + (size_t)xsub * XSUB
                        + ((n * H_ + (p + kh)) * H_ + (q + kw)) * CIN + xhalf * 4;
        async_copy16(xp, (char*)&xbuf[buf][0] + (tid & 192) * 16);
    };

    stage(0, 0);
    #pragma unroll
    for (int k = 0; k < NCH; ++k) {
        __syncthreads();               // stage(k) arrived; buf[(k+1)&1] consumed by all
        if (k + 1 < NCH) stage(k + 1, (k + 1) & 1);
        const int buf = k & 1;
        const float4* wb  = &wbuf[buf][0];
        const float4* xbp = &xbuf[buf][0];
        // subs 2sh (A) and 2sh+1 (B); [sub][half][cr] layout -> 2-way alias (free)
        const float4 xA0 = xbp[sh * 128 + cr];
        const float4 xA1 = xbp[sh * 128 + 32 + cr];
        const float4 xB0 = xbp[sh * 128 + 64 + cr];
        const float4 xB1 = xbp[sh * 128 + 96 + cr];
        const float fA[8] = {xA0.x, xA0.y, xA0.z, xA0.w, xA1.x, xA1.y, xA1.z, xA1.w};
        const float fB[8] = {xB0.x, xB0.y, xB0.z, xB0.w, xB1.x, xB1.y, xB1.z, xB1.w};
        float4 a0 = make_float4(0.f, 0.f, 0.f, 0.f);
        float4 a1 = make_float4(0.f, 0.f, 0.f, 0.f);
        #pragma unroll
        for (int i = 0; i < 8; ++i) {
            const float4 wv4 = wb[i * 128 + cr * 4 + og];   // conflict-free b128
            a0.x = fmaf(fA[i], wv4.x, a0.x);  a1.x = fmaf(fB[i], wv4.x, a1.x);
            a0.y = fmaf(fA[i], wv4.y, a0.y);  a1.y = fmaf(fB[i], wv4.y, a1.y);
            a0.z = fmaf(fA[i], wv4.z, a0.z);  a1.z = fmaf(fB[i], wv4.z, a1.z);
            a0.w = fmaf(fA[i], wv4.w, a0.w);  a1.w = fmaf(fB[i], wv4.w, a1.w);
        }
        acc[k][0] = a0;  acc[k][1] = a1;
    }

    const int sA = sh * 2;             // this thread's first sub
    float lgA[NCH], lgB[NCH];
    #pragma unroll
    for (int j = 0; j < NCH; ++j) { lgA[j] = 0.f; lgB[j] = 0.f; }

    for (int it = 0; it < NITER; ++it) {
        float4 s0 = make_float4(0.f, 0.f, 0.f, 0.f);
        float4 s1 = make_float4(0.f, 0.f, 0.f, 0.f);
        float se0 = 0.f, se1 = 0.f;

        if (it == 0) {
            #pragma unroll
            for (int j = 0; j < NCH; ++j) {
                s0.x += acc[j][0].x;  s1.x += acc[j][1].x;
                s0.y += acc[j][0].y;  s1.y += acc[j][1].y;
                s0.z += acc[j][0].z;  s1.z += acc[j][1].z;
                s0.w += acc[j][0].w;  s1.w += acc[j][1].w;
            }
        } else {
            const float4 v0 = *(const float4*)&vS[sA][og * 4];
            const float4 v1 = *(const float4*)&vS[sA + 1][og * 4];
            #pragma unroll
            for (int j = 0; j < NCH; ++j) {
                float d0 = dot4(acc[j][0], v0);
                float d1 = dot4(acc[j][1], v1);
                d0 = dpp_add_xor1(d0);  d1 = dpp_add_xor1(d1);   // VALU, not DS
                d0 = dpp_add_xor2(d0);  d1 = dpp_add_xor2(d1);
                lgA[j] += d0;                 lgB[j] += d1;
                const float e0 = __expf(lgA[j]);
                const float e1 = __expf(lgB[j]);
                se0 += e0;                    se1 += e1;
                s0.x = fmaf(e0, acc[j][0].x, s0.x);  s1.x = fmaf(e1, acc[j][1].x, s1.x);
                s0.y = fmaf(e0, acc[j][0].y, s0.y);  s1.y = fmaf(e1, acc[j][1].y, s1.y);
                s0.z = fmaf(e0, acc[j][0].z, s0.z);  s1.z = fmaf(e1, acc[j][1].z, s1.z);
                s0.w = fmaf(e0, acc[j][0].w, s0.w);  s1.w = fmaf(e1, acc[j][1].w, s1.w);
            }
            // se identical across og lanes -> reduce over rl bits (2..5) only
            #pragma unroll
            for (int off = 4; off <= 32; off <<= 1) {
                se0 += __shfl_xor(se0, off, 64);
                se1 += __shfl_xor(se1, off, 64);
            }
            if (lane == 0) { redE[wv][0] = se0; redE[wv][1] = se1; }
        }

        // reduce s over rl bits within wave (1/sum_e folded into squash)
        #pragma unroll
        for (int off = 4; off <= 32; off <<= 1) {
            s0.x += __shfl_xor(s0.x, off, 64);  s1.x += __shfl_xor(s1.x, off, 64);
            s0.y += __shfl_xor(s0.y, off, 64);  s1.y += __shfl_xor(s1.y, off, 64);
            s0.z += __shfl_xor(s0.z, off, 64);  s1.z += __shfl_xor(s1.z, off, 64);
            s0.w += __shfl_xor(s0.w, off, 64);  s1.w += __shfl_xor(s1.w, off, 64);
        }
        if (lane < 4) {   // lane == og
            *(float4*)&sRed[wv][0][lane * 4] = s0;
            *(float4*)&sRed[wv][1][lane * 4] = s1;
        }
        __syncthreads();

        // ---- squash: 64 threads = (sub 0..3, o 0..15)
        if (tid < 64) {
            const int sub = tid >> 4;
            const int o   = tid & 15;
            const int g   = sub >> 1;      // wave-pair group
            const int l   = sub & 1;       // local sub within pair
            const float inv = (it == 0)
                ? (1.0f / (float)R_)
                : 1.0f / (redE[g * 2][l] + redE[g * 2 + 1][l]);
            float s = (sRed[g * 2][l][o] + sRed[g * 2 + 1][l][o]) * inv;
            float sn = s * s;
            sn = dpp_add_xor1(sn);
            sn = dpp_add_xor2(sn);
            sn += __shfl_xor(sn, 4, 64);
            sn += __shfl_xor(sn, 8, 64);
            const float v = s * (sqrtf(sn) / (1.0f + sn));
            if (it == NITER - 1) {
                out[((((size_t)(b0 + sub) * C_ + c) * W_ + p) * W_ + q) * COUT + o] = v;
            } else {
                vS[sub][o] = v;
            }
        }
        if (it == NITER - 1) break;
        __syncthreads();   // vS visible before next iteration
    }
}

extern "C" void kernel_launch(void* const* d_in, const int* in_sizes, int n_in,
                              void* d_out, int out_size, void* d_ws, size_t ws_size,
                              hipStream_t stream) {
    const float* x  = (const float*)d_in[0];
    const float* rw = (const float*)d_in[1];
    float* out = (float*)d_out;
    dim3 grid(W_ * W_, B_ / 4, C_);
    caps_route9<<<grid, 256, 0, stream>>>(x, rw, out);
}